// Round 5
// baseline (2392.610 us; speedup 1.0000x reference)
//
#include <hip/hip_runtime.h>
#include <math.h>

// EmergentResonator — MFMA split-f16, R5.
// 256 blocks x 16 rows, 256 threads (4 waves x 6 n-tiles), 1 wave/SIMD.
// R4 lesson: pinning B_hi (144 regs) at 512thr/2-waves-per-EU budget (256 total)
// memory-spilled (WRITE_SIZE 88 MB = spill store, FETCH 3.4 GB = reloads).
// R5: __launch_bounds__(256,1) -> 512-reg unified budget; B_hi pinned = 288 regs,
// overflow absorbed by free AGPRs (cheap v_accvgpr copies / direct AGPR MFMA
// operands), NOT scratch. Only B_lo (288 KB/step/CU) streams from L2.

#define NET    360
#define NPAD   384
#define K8N    48          // NPAD/8 k8-groups for W_rec
#define RPB    16
#define NBLK   256
#define NTHR   256         // 4 waves; wave w owns n-tiles 6w..6w+5
#define NTILE  6

typedef _Float16 f16x8 __attribute__((ext_vector_type(8)));
typedef float    f32x4 __attribute__((ext_vector_type(4)));

#define WREC_E (K8N * NPAD * 8)    // 147456 f16 per term
#define WIN_E  (4 * NPAD * 8)      // 12288 f16 per term (K pad 32)

// Split fp32 weights into f16 hi/lo in MFMA B-fragment layout:
// idx = (k8*NPAD + n)*8 + (k&7), B[k][n] = W[n*K + k], zero-padded.
__global__ void prep_kernel(const float* __restrict__ W_rec,
                            const float* __restrict__ W_in,
                            const float* __restrict__ W_gate,
                            _Float16* __restrict__ Bh, _Float16* __restrict__ Bl,
                            _Float16* __restrict__ Wio)
{
    int idx = blockIdx.x * 256 + threadIdx.x;
    if (idx < WREC_E) {
        int k8 = idx / (NPAD * 8), rem = idx % (NPAD * 8);
        int n = rem >> 3, j = rem & 7, k = k8 * 8 + j;
        float v = (k < NET && n < NET) ? W_rec[n * NET + k] : 0.f;
        _Float16 h = (_Float16)v;
        Bh[idx] = h; Bl[idx] = (_Float16)(v - (float)h);
    } else if (idx < WREC_E + 2 * WIN_E) {
        // Wio layout: [0]=Wih, [1]=Wil, [2]=Wgh, [3]=Wgl, each WIN_E f16.
        int e = idx - WREC_E;                 // 0 .. 2*WIN_E-1
        int which = e / WIN_E;                // 0 = W_in, 1 = W_gate
        int f = e % WIN_E;
        int k8 = f / (NPAD * 8), rem = f % (NPAD * 8);
        int n = rem >> 3, j = rem & 7, k = k8 * 8 + j;
        const float* W = which ? W_gate : W_in;
        float v = (k < 28 && n < NET) ? W[n * 28 + k] : 0.f;
        _Float16 h = (_Float16)v;
        Wio[(2 * which) * WIN_E + f]     = h;
        Wio[(2 * which + 1) * WIN_E + f] = (_Float16)(v - (float)h);
    }
}

__device__ __forceinline__ float sigm(float v) { return 1.f / (1.f + __expf(-v)); }

__global__ __launch_bounds__(NTHR, 1)
void resonator_kernel(const float* __restrict__ x,
                      const int*   __restrict__ rsteps_p,
                      const float* __restrict__ b_in,
                      const float* __restrict__ b_gate,
                      const float* __restrict__ ln_g,
                      const float* __restrict__ ln_b,
                      const float* __restrict__ thr_p,
                      const float* __restrict__ intr_p,
                      const float* __restrict__ steep_p,
                      const float* __restrict__ reset_p,
                      const float* __restrict__ W_cls,
                      const float* __restrict__ b_cls,
                      const _Float16* __restrict__ Bh_g,
                      const _Float16* __restrict__ Bl_g,
                      const _Float16* __restrict__ Wio_g,
                      float* __restrict__ out)
{
    // Spikes in A-fragment layout, f16 hi/lo: idx = (k8*16 + m)*8 + (k&7)
    __shared__ __align__(16) _Float16 Ah[K8N * RPB * 8];   // 12 KB
    __shared__ __align__(16) _Float16 Al[K8N * RPB * 8];   // 12 KB
    __shared__ __align__(16) _Float16 xh[4 * RPB * 8];     // 1 KB  (x_t, K pad 32)
    __shared__ __align__(16) _Float16 xl[4 * RPB * 8];     // 1 KB
    __shared__ __align__(16) _Float16 Wio[4 * WIN_E];      // 96 KB: Wih,Wil,Wgh,Wgl
    __shared__ float red[4][RPB][2];
    __shared__ float musig[2][RPB];

    const int tid  = threadIdx.x;
    const int w    = tid >> 6;
    const int lane = tid & 63;
    const int quad = lane >> 4;
    const int l15  = lane & 15;
    const int row0 = blockIdx.x * RPB;

    // Per-column params for this thread's NTILE n-values (n = (w*6+i)*16 + l15)
    float gam[NTILE], bet[NTILE], thrv[NTILE], intv[NTILE], asp[NTILE], rscv[NTILE],
          binv[NTILE], bgtv[NTILE];
#pragma unroll
    for (int i = 0; i < NTILE; ++i) {
        int n_i = (w * NTILE + i) * 16 + l15;
        bool a = n_i < NET;
        gam[i]  = a ? ln_g[n_i]   : 0.f;
        bet[i]  = a ? ln_b[n_i]   : 0.f;
        thrv[i] = a ? thr_p[n_i]  : 0.f;
        intv[i] = a ? intr_p[n_i] : 0.f;
        asp[i]  = a ? fabsf(steep_p[n_i]) : 0.f;
        rscv[i] = a ? reset_p[n_i] : 0.f;
        binv[i] = a ? b_in[n_i]   : 0.f;
        bgtv[i] = a ? b_gate[n_i] : 0.f;
    }

    float pot[NTILE][4];
#pragma unroll
    for (int i = 0; i < NTILE; ++i)
#pragma unroll
        for (int r = 0; r < 4; ++r) pot[i][r] = 0.f;

    // Zero-init spike/x LDS; stage input-weight LDS from global (uint4 copies).
    for (int e = tid; e < K8N * RPB * 8; e += NTHR) { Ah[e] = (_Float16)0.f; Al[e] = (_Float16)0.f; }
    for (int e = tid; e < 4 * RPB * 8; e += NTHR)   { xh[e] = (_Float16)0.f; xl[e] = (_Float16)0.f; }
    {
        const uint4* src = (const uint4*)Wio_g;
        uint4* dst = (uint4*)Wio;
        for (int e = tid; e < (4 * WIN_E) / 8; e += NTHR) dst[e] = src[e];
    }
    __syncthreads();
    // Stage x for t=0
    for (int e = tid; e < RPB * 28; e += NTHR) {
        int m = e / 28, f = e % 28;
        float v = x[((size_t)(row0 + m) * 64 + 0) * 28 + f];
        _Float16 h = (_Float16)v;
        int ix = ((f >> 3) * RPB + m) * 8 + (f & 7);
        xh[ix] = h; xl[ix] = (_Float16)(v - (float)h);
    }

    const int Ttot = 64 + *rsteps_p;

    const f16x8* Bph = (const f16x8*)Bh_g;
    const f16x8* Bpl = (const f16x8*)Bl_g;
    const f16x8* Aph = (const f16x8*)Ah;
    const f16x8* Apl = (const f16x8*)Al;
    const f16x8* Xph = (const f16x8*)xh;
    const f16x8* Xpl = (const f16x8*)xl;
    const f16x8* Wp  = (const f16x8*)Wio;
    const int bb = quad * NPAD + w * (NTILE * 16) + l15;  // B-frag base (f16x8 units)
    const int ab = quad * RPB + l15;                      // A-frag base (f16x8 units)

    // ---- Pin step-invariant B_hi fragments: 6 tiles x 12 kt x 4 = 288 regs ----
    // (budget is 512/thread at 1 wave/SIMD; overflow -> free AGPRs, not scratch)
    f16x8 bhr[12][NTILE];
#pragma unroll
    for (int kt = 0; kt < 12; ++kt)
#pragma unroll
        for (int i = 0; i < NTILE; ++i)
            bhr[kt][i] = Bph[bb + i * 16 + kt * (4 * NPAD)];

    for (int t = 0; t < Ttot; ++t) {
        __syncthreads();   // barrier A: spikes/x for step t visible

        f32x4 acc[NTILE];
#pragma unroll
        for (int i = 0; i < NTILE; ++i) acc[i] = (f32x4){0.f, 0.f, 0.f, 0.f};

        // ---- Recurrent GEMM: acc[m][n] += sum_k spk[m][k] * W_rec[n][k] ----
        // B_hi from pinned registers; B_lo streamed from L2. Fully unrolled.
#pragma unroll
        for (int kt = 0; kt < 12; ++kt) {
            f16x8 ah = Aph[ab + kt * 64];
            f16x8 al = Apl[ab + kt * 64];
#pragma unroll
            for (int i = 0; i < NTILE; ++i) {
                f16x8 bl = Bpl[bb + i * 16 + kt * (4 * NPAD)];
                acc[i] = __builtin_amdgcn_mfma_f32_16x16x32_f16(ah, bhr[kt][i], acc[i], 0, 0, 0);
                acc[i] = __builtin_amdgcn_mfma_f32_16x16x32_f16(al, bhr[kt][i], acc[i], 0, 0, 0);
                acc[i] = __builtin_amdgcn_mfma_f32_16x16x32_f16(ah, bl,         acc[i], 0, 0, 0);
            }
        }

        // ---- Gated input via MFMA from LDS weights (scan phase) ----
        if (t < 64) {
            f16x8 xa = Xph[ab];
            f16x8 xb = Xpl[ab];
#pragma unroll
            for (int i = 0; i < NTILE; ++i) {
                f16x8 ih = Wp[0 * (WIN_E / 8) + bb + i * 16];
                f16x8 il = Wp[1 * (WIN_E / 8) + bb + i * 16];
                f16x8 gh = Wp[2 * (WIN_E / 8) + bb + i * 16];
                f16x8 gl = Wp[3 * (WIN_E / 8) + bb + i * 16];
                f32x4 ia = (f32x4){binv[i], binv[i], binv[i], binv[i]};
                f32x4 ga = (f32x4){bgtv[i], bgtv[i], bgtv[i], bgtv[i]};
                ia = __builtin_amdgcn_mfma_f32_16x16x32_f16(xa, ih, ia, 0, 0, 0);
                ia = __builtin_amdgcn_mfma_f32_16x16x32_f16(xb, ih, ia, 0, 0, 0);
                ia = __builtin_amdgcn_mfma_f32_16x16x32_f16(xa, il, ia, 0, 0, 0);
                ga = __builtin_amdgcn_mfma_f32_16x16x32_f16(xa, gh, ga, 0, 0, 0);
                ga = __builtin_amdgcn_mfma_f32_16x16x32_f16(xb, gh, ga, 0, 0, 0);
                ga = __builtin_amdgcn_mfma_f32_16x16x32_f16(xa, gl, ga, 0, 0, 0);
#pragma unroll
                for (int r = 0; r < 4; ++r) acc[i][r] += ia[r] * sigm(ga[r]);
            }
        }

        // ---- LayerNorm stats: reduce over n (16 l15-lanes, then 4 waves) ----
#pragma unroll
        for (int r = 0; r < 4; ++r) {
            float v = 0.f, v2 = 0.f;
#pragma unroll
            for (int i = 0; i < NTILE; ++i) { v += acc[i][r]; v2 += acc[i][r] * acc[i][r]; }
#pragma unroll
            for (int off = 1; off < 16; off <<= 1) {
                v  += __shfl_xor(v,  off);
                v2 += __shfl_xor(v2, off);
            }
            if (l15 == 0) { red[w][quad * 4 + r][0] = v; red[w][quad * 4 + r][1] = v2; }
        }
        __syncthreads();   // barrier B
        if (tid < RPB) {
            float s = 0.f, s2 = 0.f;
#pragma unroll
            for (int w2 = 0; w2 < 4; ++w2) { s += red[w2][tid][0]; s2 += red[w2][tid][1]; }
            float mu  = s * (1.f / NET);
            float var = s2 * (1.f / NET) - mu * mu;
            musig[0][tid] = mu;
            musig[1][tid] = rsqrtf(var + 1e-5f);
        }
        __syncthreads();   // barrier C

        float mu_r[4], rs_r[4];
#pragma unroll
        for (int r = 0; r < 4; ++r) { mu_r[r] = musig[0][quad * 4 + r]; rs_r[r] = musig[1][quad * 4 + r]; }

        // ---- LN apply + PulseTGAU neuron, write split spikes to A-layout ----
#pragma unroll
        for (int i = 0; i < NTILE; ++i) {
            int n_i  = (w * NTILE + i) * 16 + l15;
            int base = ((n_i >> 3) * RPB) * 8 + (n_i & 7);
#pragma unroll
            for (int r = 0; r < 4; ++r) {
                int m = quad * 4 + r;
                float cur = (acc[i][r] - mu_r[r]) * rs_r[r] * gam[i] + bet[i];
                float p   = pot[i][r] * 0.95f + cur + intv[i];
                float gp  = p - thrv[i];
                float sg  = sigm(gp * asp[i]);
                float sp  = sigm(gp);
                float o   = gp * sp * sg;
                pot[i][r] = p - rscv[i] * (gp * sg);
                _Float16 h = (_Float16)o;
                Ah[base + m * 8] = h;
                Al[base + m * 8] = (_Float16)(o - (float)h);
            }
        }

        // Stage x for t+1 (xh reads for step t all happened before barrier B)
        if (t < 63) {
            for (int e = tid; e < RPB * 28; e += NTHR) {
                int m = e / 28, f = e % 28;
                float v = x[((size_t)(row0 + m) * 64 + (t + 1)) * 28 + f];
                _Float16 h = (_Float16)v;
                int ix = ((f >> 3) * RPB + m) * 8 + (f & 7);
                xh[ix] = h; xl[ix] = (_Float16)(v - (float)h);
            }
        }
    }

    __syncthreads();
    // ---- Classifier epilogue ----
    if (tid < RPB * 10) {
        int r = tid / 10, c = tid - r * 10;
        const float* wc = W_cls + c * NET;
        float s = b_cls[c];
        for (int k = 0; k < NET; ++k) {
            int ix = ((k >> 3) * RPB + r) * 8 + (k & 7);
            float sv = (float)Ah[ix] + (float)Al[ix];
            s = fmaf(sv, wc[k], s);
        }
        out[(size_t)(row0 + r) * 10 + c] = s;
    }
}

extern "C" void kernel_launch(void* const* d_in, const int* in_sizes, int n_in,
                              void* d_out, int out_size, void* d_ws, size_t ws_size,
                              hipStream_t stream)
{
    const float* x      = (const float*)d_in[0];
    const int*   rsteps = (const int*)  d_in[1];
    const float* W_in   = (const float*)d_in[2];
    const float* b_in   = (const float*)d_in[3];
    const float* W_gate = (const float*)d_in[4];
    const float* b_gate = (const float*)d_in[5];
    const float* W_rec  = (const float*)d_in[6];
    const float* ln_g   = (const float*)d_in[7];
    const float* ln_b   = (const float*)d_in[8];
    const float* thr    = (const float*)d_in[9];
    const float* intr   = (const float*)d_in[10];
    const float* steep  = (const float*)d_in[11];
    const float* rsc    = (const float*)d_in[12];
    const float* W_cls  = (const float*)d_in[13];
    const float* b_cls  = (const float*)d_in[14];
    float*       out    = (float*)d_out;

    _Float16* Bh  = (_Float16*)d_ws;
    _Float16* Bl  = Bh + WREC_E;
    _Float16* Wio = Bl + WREC_E;     // 4*WIN_E: Wih, Wil, Wgh, Wgl

    const int total = WREC_E + 2 * WIN_E;
    prep_kernel<<<dim3((total + 255) / 256), dim3(256), 0, stream>>>(
        W_rec, W_in, W_gate, Bh, Bl, Wio);
    resonator_kernel<<<dim3(NBLK), dim3(NTHR), 0, stream>>>(
        x, rsteps, b_in, b_gate, ln_g, ln_b, thr, intr, steep, rsc,
        W_cls, b_cls, Bh, Bl, Wio, out);
}

// Round 6
// 1623.465 us; speedup vs baseline: 1.4738x; 1.4738x over previous
//
#include <hip/hip_runtime.h>
#include <math.h>

// EmergentResonator — MFMA split-f16, R6.
// Base = R3 (767 us, no spills, VGPR=88). Changes:
//  1. 5-kt-group B prefetch (120 regs, SHORT live range: neuron(t) -> early GEMM(t+1))
//     so ~215 KB of the step-invariant W_rec stream flows under the VALU tail +
//     barrier drain instead of serializing in the GEMM phase.
//  2. Barrier C removed: LN finalize computed redundantly by all threads from a
//     float2 LDS table (broadcast reads), instead of tid<16 + extra barrier.
//  3. waves_per_eu(2,2) pins the register budget at 256 (R4/R5 lesson: allocator
//     never uses AGPRs for operand arrays; stay under the 256 arch cap).

#define NET    360
#define NPAD   384
#define K8N    48
#define RPB    16
#define NBLK   256
#define NTHR   512         // 8 waves; wave w owns n-tiles 3w..3w+2
#define NTILE  3
#define PREG   5           // prefetched kt-groups (of 12)

typedef _Float16 f16x8 __attribute__((ext_vector_type(8)));
typedef float    f32x4 __attribute__((ext_vector_type(4)));

#define WREC_E (K8N * NPAD * 8)    // 147456 f16 per term
#define WIN_E  (4 * NPAD * 8)      // 12288 f16 per term (K pad 32)

// Split fp32 weights into f16 hi/lo in MFMA B-fragment layout:
// idx = (k8*NPAD + n)*8 + (k&7), B[k][n] = W[n*K + k], zero-padded.
__global__ void prep_kernel(const float* __restrict__ W_rec,
                            const float* __restrict__ W_in,
                            const float* __restrict__ W_gate,
                            _Float16* __restrict__ Bh, _Float16* __restrict__ Bl,
                            _Float16* __restrict__ Wio)
{
    int idx = blockIdx.x * 256 + threadIdx.x;
    if (idx < WREC_E) {
        int k8 = idx / (NPAD * 8), rem = idx % (NPAD * 8);
        int n = rem >> 3, j = rem & 7, k = k8 * 8 + j;
        float v = (k < NET && n < NET) ? W_rec[n * NET + k] : 0.f;
        _Float16 h = (_Float16)v;
        Bh[idx] = h; Bl[idx] = (_Float16)(v - (float)h);
    } else if (idx < WREC_E + 2 * WIN_E) {
        int e = idx - WREC_E;
        int which = e / WIN_E;                // 0 = W_in, 1 = W_gate
        int f = e % WIN_E;
        int k8 = f / (NPAD * 8), rem = f % (NPAD * 8);
        int n = rem >> 3, j = rem & 7, k = k8 * 8 + j;
        const float* W = which ? W_gate : W_in;
        float v = (k < 28 && n < NET) ? W[n * 28 + k] : 0.f;
        _Float16 h = (_Float16)v;
        Wio[(2 * which) * WIN_E + f]     = h;
        Wio[(2 * which + 1) * WIN_E + f] = (_Float16)(v - (float)h);
    }
}

__device__ __forceinline__ float sigm(float v) { return 1.f / (1.f + __expf(-v)); }

__global__ __launch_bounds__(NTHR, 2) __attribute__((amdgpu_waves_per_eu(2, 2)))
void resonator_kernel(const float* __restrict__ x,
                      const int*   __restrict__ rsteps_p,
                      const float* __restrict__ b_in,
                      const float* __restrict__ b_gate,
                      const float* __restrict__ ln_g,
                      const float* __restrict__ ln_b,
                      const float* __restrict__ thr_p,
                      const float* __restrict__ intr_p,
                      const float* __restrict__ steep_p,
                      const float* __restrict__ reset_p,
                      const float* __restrict__ W_cls,
                      const float* __restrict__ b_cls,
                      const _Float16* __restrict__ Bh_g,
                      const _Float16* __restrict__ Bl_g,
                      const _Float16* __restrict__ Wio_g,
                      float* __restrict__ out)
{
    // Spikes in A-fragment layout, f16 hi/lo: idx = (k8*16 + m)*8 + (k&7)
    __shared__ __align__(16) _Float16 Ah[K8N * RPB * 8];   // 12 KB
    __shared__ __align__(16) _Float16 Al[K8N * RPB * 8];   // 12 KB
    __shared__ __align__(16) _Float16 xh[4 * RPB * 8];     // 1 KB
    __shared__ __align__(16) _Float16 xl[4 * RPB * 8];     // 1 KB
    __shared__ __align__(16) _Float16 Wio[4 * WIN_E];      // 96 KB
    __shared__ float2 red2[8][RPB];                        // per-wave LN partials

    const int tid  = threadIdx.x;
    const int w    = tid >> 6;
    const int lane = tid & 63;
    const int quad = lane >> 4;
    const int l15  = lane & 15;
    const int row0 = blockIdx.x * RPB;

    float gam[NTILE], bet[NTILE], thrv[NTILE], intv[NTILE], asp[NTILE], rscv[NTILE],
          binv[NTILE], bgtv[NTILE];
#pragma unroll
    for (int i = 0; i < NTILE; ++i) {
        int n_i = (w * NTILE + i) * 16 + l15;
        bool a = n_i < NET;
        gam[i]  = a ? ln_g[n_i]   : 0.f;
        bet[i]  = a ? ln_b[n_i]   : 0.f;
        thrv[i] = a ? thr_p[n_i]  : 0.f;
        intv[i] = a ? intr_p[n_i] : 0.f;
        asp[i]  = a ? fabsf(steep_p[n_i]) : 0.f;
        rscv[i] = a ? reset_p[n_i] : 0.f;
        binv[i] = a ? b_in[n_i]   : 0.f;
        bgtv[i] = a ? b_gate[n_i] : 0.f;
    }

    float pot[NTILE][4];
#pragma unroll
    for (int i = 0; i < NTILE; ++i)
#pragma unroll
        for (int r = 0; r < 4; ++r) pot[i][r] = 0.f;

    for (int e = tid; e < K8N * RPB * 8; e += NTHR) { Ah[e] = (_Float16)0.f; Al[e] = (_Float16)0.f; }
    for (int e = tid; e < 4 * RPB * 8; e += NTHR)   { xh[e] = (_Float16)0.f; xl[e] = (_Float16)0.f; }
    {
        const uint4* src = (const uint4*)Wio_g;
        uint4* dst = (uint4*)Wio;
        for (int e = tid; e < (4 * WIN_E) / 8; e += NTHR) dst[e] = src[e];
    }
    __syncthreads();
    for (int e = tid; e < RPB * 28; e += NTHR) {
        int m = e / 28, f = e % 28;
        float v = x[((size_t)(row0 + m) * 64 + 0) * 28 + f];
        _Float16 h = (_Float16)v;
        int ix = ((f >> 3) * RPB + m) * 8 + (f & 7);
        xh[ix] = h; xl[ix] = (_Float16)(v - (float)h);
    }

    const int Ttot = 64 + *rsteps_p;

    const f16x8* Bph = (const f16x8*)Bh_g;
    const f16x8* Bpl = (const f16x8*)Bl_g;
    const f16x8* Aph = (const f16x8*)Ah;
    const f16x8* Apl = (const f16x8*)Al;
    const f16x8* Xph = (const f16x8*)xh;
    const f16x8* Xpl = (const f16x8*)xl;
    const f16x8* Wp  = (const f16x8*)Wio;
    const int bb = quad * NPAD + w * (NTILE * 16) + l15;
    const int ab = quad * RPB + l15;

    // Prefetch window: groups 0..PREG-1 of the next step's B stream.
    // Live range deliberately short (reloaded each iteration, consumed early).
    f16x8 pre_h[PREG][NTILE], pre_l[PREG][NTILE];
#pragma unroll
    for (int g = 0; g < PREG; ++g)
#pragma unroll
        for (int i = 0; i < NTILE; ++i) {
            pre_h[g][i] = Bph[bb + i * 16 + g * (4 * NPAD)];
            pre_l[g][i] = Bpl[bb + i * 16 + g * (4 * NPAD)];
        }

    for (int t = 0; t < Ttot; ++t) {
        __syncthreads();   // barrier A: spikes/x visible; prefetch loads drained

        f32x4 acc[NTILE];
#pragma unroll
        for (int i = 0; i < NTILE; ++i) acc[i] = (f32x4){0.f, 0.f, 0.f, 0.f};

        // ---- Recurrent GEMM, prefetched groups first (regs already valid) ----
#pragma unroll
        for (int g = 0; g < PREG; ++g) {
            f16x8 ah = Aph[ab + g * 64];
            f16x8 al = Apl[ab + g * 64];
#pragma unroll
            for (int i = 0; i < NTILE; ++i) {
                acc[i] = __builtin_amdgcn_mfma_f32_16x16x32_f16(ah, pre_h[g][i], acc[i], 0, 0, 0);
                acc[i] = __builtin_amdgcn_mfma_f32_16x16x32_f16(al, pre_h[g][i], acc[i], 0, 0, 0);
                acc[i] = __builtin_amdgcn_mfma_f32_16x16x32_f16(ah, pre_l[g][i], acc[i], 0, 0, 0);
            }
        }
        // ---- Streamed groups ----
#pragma unroll
        for (int kt = PREG; kt < 12; ++kt) {
            f16x8 ah = Aph[ab + kt * 64];
            f16x8 al = Apl[ab + kt * 64];
#pragma unroll
            for (int i = 0; i < NTILE; ++i) {
                f16x8 bh = Bph[bb + i * 16 + kt * (4 * NPAD)];
                f16x8 bl = Bpl[bb + i * 16 + kt * (4 * NPAD)];
                acc[i] = __builtin_amdgcn_mfma_f32_16x16x32_f16(ah, bh, acc[i], 0, 0, 0);
                acc[i] = __builtin_amdgcn_mfma_f32_16x16x32_f16(al, bh, acc[i], 0, 0, 0);
                acc[i] = __builtin_amdgcn_mfma_f32_16x16x32_f16(ah, bl, acc[i], 0, 0, 0);
            }
        }

        // ---- Gated input via MFMA from LDS weights (scan phase) ----
        if (t < 64) {
            f16x8 xa = Xph[ab];
            f16x8 xb = Xpl[ab];
#pragma unroll
            for (int i = 0; i < NTILE; ++i) {
                f16x8 ih = Wp[0 * (WIN_E / 8) + bb + i * 16];
                f16x8 il = Wp[1 * (WIN_E / 8) + bb + i * 16];
                f16x8 gh = Wp[2 * (WIN_E / 8) + bb + i * 16];
                f16x8 gl = Wp[3 * (WIN_E / 8) + bb + i * 16];
                f32x4 ia = (f32x4){binv[i], binv[i], binv[i], binv[i]};
                f32x4 ga = (f32x4){bgtv[i], bgtv[i], bgtv[i], bgtv[i]};
                ia = __builtin_amdgcn_mfma_f32_16x16x32_f16(xa, ih, ia, 0, 0, 0);
                ia = __builtin_amdgcn_mfma_f32_16x16x32_f16(xb, ih, ia, 0, 0, 0);
                ia = __builtin_amdgcn_mfma_f32_16x16x32_f16(xa, il, ia, 0, 0, 0);
                ga = __builtin_amdgcn_mfma_f32_16x16x32_f16(xa, gh, ga, 0, 0, 0);
                ga = __builtin_amdgcn_mfma_f32_16x16x32_f16(xb, gh, ga, 0, 0, 0);
                ga = __builtin_amdgcn_mfma_f32_16x16x32_f16(xa, gl, ga, 0, 0, 0);
#pragma unroll
                for (int r = 0; r < 4; ++r) acc[i][r] += ia[r] * sigm(ga[r]);
            }
        }

        // ---- LN stats: 16-lane shfl reduce, one LDS table, ONE barrier ----
#pragma unroll
        for (int r = 0; r < 4; ++r) {
            float v = 0.f, v2 = 0.f;
#pragma unroll
            for (int i = 0; i < NTILE; ++i) { v += acc[i][r]; v2 += acc[i][r] * acc[i][r]; }
#pragma unroll
            for (int off = 1; off < 16; off <<= 1) {
                v  += __shfl_xor(v,  off);
                v2 += __shfl_xor(v2, off);
            }
            if (l15 == 0) red2[w][quad * 4 + r] = make_float2(v, v2);
        }
        __syncthreads();   // barrier B

        // Redundant finalize (every thread; broadcast LDS reads, no barrier C)
        float mu_r[4], rs_r[4];
#pragma unroll
        for (int r = 0; r < 4; ++r) {
            float s = 0.f, s2 = 0.f;
#pragma unroll
            for (int w2 = 0; w2 < 8; ++w2) {
                float2 e = red2[w2][quad * 4 + r];
                s += e.x; s2 += e.y;
            }
            float mu  = s * (1.f / NET);
            float var = s2 * (1.f / NET) - mu * mu;
            mu_r[r] = mu;
            rs_r[r] = rsqrtf(var + 1e-5f);
        }

        // ---- LN apply + PulseTGAU neuron, write split spikes to A-layout ----
#pragma unroll
        for (int i = 0; i < NTILE; ++i) {
            int n_i  = (w * NTILE + i) * 16 + l15;
            int base = ((n_i >> 3) * RPB) * 8 + (n_i & 7);
#pragma unroll
            for (int r = 0; r < 4; ++r) {
                int m = quad * 4 + r;
                float cur = (acc[i][r] - mu_r[r]) * rs_r[r] * gam[i] + bet[i];
                float p   = pot[i][r] * 0.95f + cur + intv[i];
                float gp  = p - thrv[i];
                float sg  = sigm(gp * asp[i]);
                float sp  = sigm(gp);
                float gs  = gp * sg;
                float o   = gs * sp;
                pot[i][r] = p - rscv[i] * gs;
                _Float16 h = (_Float16)o;
                Ah[base + m * 8] = h;
                Al[base + m * 8] = (_Float16)(o - (float)h);
            }
        }

        // Stage x for t+1
        if (t < 63) {
            for (int e = tid; e < RPB * 28; e += NTHR) {
                int m = e / 28, f = e % 28;
                float v = x[((size_t)(row0 + m) * 64 + (t + 1)) * 28 + f];
                _Float16 h = (_Float16)v;
                int ix = ((f >> 3) * RPB + m) * 8 + (f & 7);
                xh[ix] = h; xl[ix] = (_Float16)(v - (float)h);
            }
        }

        // ---- Prefetch next step's first PREG B-groups (flows under the tail
        //      phases + barrier-A drain; same bytes every step) ----
#pragma unroll
        for (int g = 0; g < PREG; ++g)
#pragma unroll
            for (int i = 0; i < NTILE; ++i) {
                pre_h[g][i] = Bph[bb + i * 16 + g * (4 * NPAD)];
                pre_l[g][i] = Bpl[bb + i * 16 + g * (4 * NPAD)];
            }
    }

    __syncthreads();
    // ---- Classifier epilogue ----
    if (tid < RPB * 10) {
        int r = tid / 10, c = tid - r * 10;
        const float* wc = W_cls + c * NET;
        float s = b_cls[c];
        for (int k = 0; k < NET; ++k) {
            int ix = ((k >> 3) * RPB + r) * 8 + (k & 7);
            float sv = (float)Ah[ix] + (float)Al[ix];
            s = fmaf(sv, wc[k], s);
        }
        out[(size_t)(row0 + r) * 10 + c] = s;
    }
}

extern "C" void kernel_launch(void* const* d_in, const int* in_sizes, int n_in,
                              void* d_out, int out_size, void* d_ws, size_t ws_size,
                              hipStream_t stream)
{
    const float* x      = (const float*)d_in[0];
    const int*   rsteps = (const int*)  d_in[1];
    const float* W_in   = (const float*)d_in[2];
    const float* b_in   = (const float*)d_in[3];
    const float* W_gate = (const float*)d_in[4];
    const float* b_gate = (const float*)d_in[5];
    const float* W_rec  = (const float*)d_in[6];
    const float* ln_g   = (const float*)d_in[7];
    const float* ln_b   = (const float*)d_in[8];
    const float* thr    = (const float*)d_in[9];
    const float* intr   = (const float*)d_in[10];
    const float* steep  = (const float*)d_in[11];
    const float* rsc    = (const float*)d_in[12];
    const float* W_cls  = (const float*)d_in[13];
    const float* b_cls  = (const float*)d_in[14];
    float*       out    = (float*)d_out;

    _Float16* Bh  = (_Float16*)d_ws;
    _Float16* Bl  = Bh + WREC_E;
    _Float16* Wio = Bl + WREC_E;

    const int total = WREC_E + 2 * WIN_E;
    prep_kernel<<<dim3((total + 255) / 256), dim3(256), 0, stream>>>(
        W_rec, W_in, W_gate, Bh, Bl, Wio);
    resonator_kernel<<<dim3(NBLK), dim3(NTHR), 0, stream>>>(
        x, rsteps, b_in, b_gate, ln_g, ln_b, thr, intr, steep, rsc,
        W_cls, b_cls, Bh, Bl, Wio, out);
}

// Round 8
// 1120.869 us; speedup vs baseline: 2.1346x; 1.4484x over previous
//
#include <hip/hip_runtime.h>
#include <math.h>
#include <stdint.h>

// EmergentResonator — R8: wrap-around LDS-DMA double-buffer pipeline, full split-f16.
// R7 post-mortem: (a) Wio slot bug fed W_in-lo as W_gate; (b) size-12 DMA is not
// HW-verified + refill could race the staged reads -> NaN from uninit LDS.
// R8: contiguous per-(wave,group) BW layout -> 16B DMAs only; vmcnt(6) waits that
// are correct under in-order retirement regardless of compiler-injected loads;
// explicit lgkmcnt(0) between staged reads and the refill; groups 10/11 refill the
// NEXT step's groups 0/1 so the stream flows under the tail (lgkm-only barriers).
// Precision identical to R3 (hi+lo everywhere): absmax expected 0.0078.

#define NET    360
#define NPAD   384
#define RPB    16
#define NBLK   256
#define NTHR   512
#define NTILE  3
#define NWAVE  8
#define WSLICE 3072                   // f16 per (wave, group): 4 k8 x 48 n x 8 x {hi,lo}
#define BW_E   (NWAVE * 12 * WSLICE)  // 294912 f16
#define WIN_E  (4 * NPAD * 8)         // 12288 f16 per input-weight term

typedef _Float16 f16x8 __attribute__((ext_vector_type(8)));
typedef float    f32x4 __attribute__((ext_vector_type(4)));
typedef const __attribute__((address_space(1))) void gas_void;
typedef __attribute__((address_space(3))) void las_void;

// BW layout: idx = ((w*12 + g)*2 + term)*1536 + (kq*48 + nn)*8 + j
//   k8 = g*4 + kq, k = k8*8 + j, n = w*48 + nn; value = W_rec[n][k] (zero-pad).
// Wio layout: mat (0=Wih,1=Wil,2=Wgh,3=Wgl) * WIN_E + (k8*NPAD + n)*8 + j.
__global__ void prep_kernel(const float* __restrict__ W_rec,
                            const float* __restrict__ W_in,
                            const float* __restrict__ W_gate,
                            _Float16* __restrict__ BW,
                            _Float16* __restrict__ Wio)
{
    int idx = blockIdx.x * 256 + threadIdx.x;
    if (idx < BW_E) {
        int w    = idx / (12 * WSLICE);
        int r    = idx % (12 * WSLICE);
        int g    = r / WSLICE;
        int r2   = r % WSLICE;
        int term = r2 / 1536;
        int r3   = r2 % 1536;
        int kq   = r3 / 384;
        int r4   = r3 % 384;
        int nn = r4 >> 3, j = r4 & 7;
        int k = (g * 4 + kq) * 8 + j;
        int n = w * 48 + nn;
        float v = (k < NET && n < NET) ? W_rec[n * NET + k] : 0.f;
        _Float16 h = (_Float16)v;
        BW[idx] = term ? (_Float16)(v - (float)h) : h;
    } else if (idx < BW_E + 4 * WIN_E) {
        int e = idx - BW_E;
        int mat = e / WIN_E;
        int f = e % WIN_E;
        int k8 = f / (NPAD * 8), rem = f % (NPAD * 8);
        int n = rem >> 3, j = rem & 7, k = k8 * 8 + j;
        const float* W = (mat < 2) ? W_in : W_gate;
        float v = (k < 28 && n < NET) ? W[n * 28 + k] : 0.f;
        _Float16 h = (_Float16)v;
        Wio[e] = (mat & 1) ? (_Float16)(v - (float)h) : h;
    }
}

__device__ __forceinline__ float sigm(float v) { return 1.f / (1.f + __expf(-v)); }

// Stage group gg for wave w into staging buffer buf: 6 x 16B-per-lane DMAs,
// source fully contiguous (identity map global -> LDS slice).
__device__ __forceinline__ void dma6(const _Float16* __restrict__ BW,
                                     _Float16* __restrict__ SB,
                                     int gg, int buf, int w, int lane)
{
    const _Float16* src = BW + (w * 12 + gg) * WSLICE + lane * 8;
    _Float16* dst = SB + (buf * NWAVE + w) * WSLICE;
#pragma unroll
    for (int c = 0; c < 6; ++c)
        __builtin_amdgcn_global_load_lds((gas_void*)(src + c * 512),
                                         (las_void*)(dst + c * 512), 16, 0, 0);
}

__global__ __launch_bounds__(NTHR, 2)
void resonator_kernel(const float* __restrict__ x,
                      const int*   __restrict__ rsteps_p,
                      const float* __restrict__ b_in,
                      const float* __restrict__ b_gate,
                      const float* __restrict__ ln_g,
                      const float* __restrict__ ln_b,
                      const float* __restrict__ thr_p,
                      const float* __restrict__ intr_p,
                      const float* __restrict__ steep_p,
                      const float* __restrict__ reset_p,
                      const float* __restrict__ W_cls,
                      const float* __restrict__ b_cls,
                      const _Float16* __restrict__ BW,
                      const _Float16* __restrict__ WioG,
                      float* __restrict__ out)
{
    __shared__ __align__(16) _Float16 SB[2 * NWAVE * WSLICE];  // 96 KB staging ring
    __shared__ __align__(16) _Float16 Ah[48 * RPB * 8];        // 12 KB spikes hi
    __shared__ __align__(16) _Float16 Al[48 * RPB * 8];        // 12 KB spikes lo
    __shared__ __align__(16) _Float16 xh[4 * RPB * 8];         // 1 KB
    __shared__ __align__(16) _Float16 xl[4 * RPB * 8];         // 1 KB
    __shared__ float2 red2[NWAVE][RPB];                        // 1 KB

    const int tid  = threadIdx.x;
    const int w    = tid >> 6;
    const int lane = tid & 63;
    const int quad = lane >> 4;
    const int l15  = lane & 15;
    const int row0 = blockIdx.x * RPB;

    float gam[NTILE], bet[NTILE], thrv[NTILE], intv[NTILE], asp[NTILE], rscv[NTILE],
          binv[NTILE], bgtv[NTILE];
#pragma unroll
    for (int i = 0; i < NTILE; ++i) {
        int n_i = (w * NTILE + i) * 16 + l15;
        bool a = n_i < NET;
        gam[i]  = a ? ln_g[n_i]   : 0.f;
        bet[i]  = a ? ln_b[n_i]   : 0.f;
        thrv[i] = a ? thr_p[n_i]  : 0.f;
        intv[i] = a ? intr_p[n_i] : 0.f;
        asp[i]  = a ? fabsf(steep_p[n_i]) : 0.f;
        rscv[i] = a ? reset_p[n_i] : 0.f;
        binv[i] = a ? b_in[n_i]   : 0.f;
        bgtv[i] = a ? b_gate[n_i] : 0.f;
    }

    float pot[NTILE][4];
#pragma unroll
    for (int i = 0; i < NTILE; ++i)
#pragma unroll
        for (int r = 0; r < 4; ++r) pot[i][r] = 0.f;

    for (int e = tid; e < 48 * RPB * 8; e += NTHR) { Ah[e] = (_Float16)0.f; Al[e] = (_Float16)0.f; }
    for (int e = tid; e < 4 * RPB * 8; e += NTHR)  { xh[e] = (_Float16)0.f; xl[e] = (_Float16)0.f; }
    __syncthreads();

    const int Ttot = 64 + *rsteps_p;

    // Stage x(t=0), then prime the ring with groups 0,1.
    if (tid < RPB * 28) {
        int m = tid / 28, f = tid % 28;
        float v = x[((size_t)(row0 + m) * 64 + 0) * 28 + f];
        _Float16 h = (_Float16)v;
        int ix = ((f >> 3) * RPB + m) * 8 + (f & 7);
        xh[ix] = h; xl[ix] = (_Float16)(v - (float)h);
    }
    dma6(BW, SB, 0, 0, w, lane);
    dma6(BW, SB, 1, 1, w, lane);

    const f16x8* Aph = (const f16x8*)Ah;
    const f16x8* Apl = (const f16x8*)Al;
    const f16x8* Xph = (const f16x8*)xh;
    const f16x8* Xpl = (const f16x8*)xl;
    const f16x8* WP  = (const f16x8*)WioG;
    const int abq = quad * RPB + l15;                // A-frag base (f16x8 units)
    const int fb  = quad * NPAD + w * 48 + l15;      // Wio frag base (f16x8 units)

    for (int t = 0; t < Ttot; ++t) {
        // barrier A: lgkm-only drain (spike/x ds_writes) — DMAs stay in flight.
        asm volatile("s_waitcnt lgkmcnt(0)\n\ts_barrier" ::: "memory");

        f32x4 acc[NTILE];
#pragma unroll
        for (int i = 0; i < NTILE; ++i) acc[i] = (f32x4){0.f, 0.f, 0.f, 0.f};

        // ---- Gated input (scan phase): hi+lo weights streamed from L2 ----
        if (t < 64) {
            f16x8 xa = Xph[abq];
            f16x8 xb = Xpl[abq];
#pragma unroll
            for (int i = 0; i < NTILE; ++i) {
                f16x8 ih = WP[0 * 1536 + fb + i * 16];
                f16x8 il = WP[1 * 1536 + fb + i * 16];
                f16x8 gh = WP[2 * 1536 + fb + i * 16];
                f16x8 gl = WP[3 * 1536 + fb + i * 16];
                f32x4 ia = (f32x4){binv[i], binv[i], binv[i], binv[i]};
                f32x4 ga = (f32x4){bgtv[i], bgtv[i], bgtv[i], bgtv[i]};
                ia = __builtin_amdgcn_mfma_f32_16x16x32_f16(xa, ih, ia, 0, 0, 0);
                ia = __builtin_amdgcn_mfma_f32_16x16x32_f16(xb, ih, ia, 0, 0, 0);
                ia = __builtin_amdgcn_mfma_f32_16x16x32_f16(xa, il, ia, 0, 0, 0);
                ga = __builtin_amdgcn_mfma_f32_16x16x32_f16(xa, gh, ga, 0, 0, 0);
                ga = __builtin_amdgcn_mfma_f32_16x16x32_f16(xb, gh, ga, 0, 0, 0);
                ga = __builtin_amdgcn_mfma_f32_16x16x32_f16(xa, gl, ga, 0, 0, 0);
#pragma unroll
                for (int r = 0; r < 4; ++r) acc[i][r] += ia[r] * sigm(ga[r]);
            }
        }

        // ---- Recurrent GEMM: 12 groups, wrap-around double-buffer pipeline ----
#pragma unroll
        for (int g = 0; g < 12; ++g) {
            const int buf = g & 1;
            f16x8 ah = Aph[abq + g * 64];
            f16x8 al = Apl[abq + g * 64];
            // All issues older than group g+1's refill have landed => buf valid.
            asm volatile("s_waitcnt vmcnt(6)" ::: "memory");
            const f16x8* sbw = (const f16x8*)SB + (buf * NWAVE + w) * (WSLICE / 8)
                             + quad * 48 + l15;
            f16x8 bh0 = sbw[0 * 16],      bh1 = sbw[1 * 16],      bh2 = sbw[2 * 16];
            f16x8 bl0 = sbw[192 + 0 * 16], bl1 = sbw[192 + 1 * 16], bl2 = sbw[192 + 2 * 16];
            // Guarantee staged reads complete before the refill can overwrite.
            asm volatile("s_waitcnt lgkmcnt(0)" ::: "memory");
            int gg = g + 2; if (gg >= 12) gg -= 12;   // 10,11 -> next step's 0,1
            dma6(BW, SB, gg, buf, w, lane);
            acc[0] = __builtin_amdgcn_mfma_f32_16x16x32_f16(ah, bh0, acc[0], 0, 0, 0);
            acc[0] = __builtin_amdgcn_mfma_f32_16x16x32_f16(al, bh0, acc[0], 0, 0, 0);
            acc[0] = __builtin_amdgcn_mfma_f32_16x16x32_f16(ah, bl0, acc[0], 0, 0, 0);
            acc[1] = __builtin_amdgcn_mfma_f32_16x16x32_f16(ah, bh1, acc[1], 0, 0, 0);
            acc[1] = __builtin_amdgcn_mfma_f32_16x16x32_f16(al, bh1, acc[1], 0, 0, 0);
            acc[1] = __builtin_amdgcn_mfma_f32_16x16x32_f16(ah, bl1, acc[1], 0, 0, 0);
            acc[2] = __builtin_amdgcn_mfma_f32_16x16x32_f16(ah, bh2, acc[2], 0, 0, 0);
            acc[2] = __builtin_amdgcn_mfma_f32_16x16x32_f16(al, bh2, acc[2], 0, 0, 0);
            acc[2] = __builtin_amdgcn_mfma_f32_16x16x32_f16(ah, bl2, acc[2], 0, 0, 0);
        }

        // ---- LN stats ----
#pragma unroll
        for (int r = 0; r < 4; ++r) {
            float v = 0.f, v2 = 0.f;
#pragma unroll
            for (int i = 0; i < NTILE; ++i) { v += acc[i][r]; v2 += acc[i][r] * acc[i][r]; }
#pragma unroll
            for (int off = 1; off < 16; off <<= 1) {
                v  += __shfl_xor(v,  off);
                v2 += __shfl_xor(v2, off);
            }
            if (l15 == 0) red2[w][quad * 4 + r] = make_float2(v, v2);
        }

        // Next-step x load issued early (its wait only over-drains landed DMAs).
        const bool do_x = (t < 63) && (tid < RPB * 28);
        float xv = 0.f;
        if (do_x) xv = x[((size_t)(row0 + tid / 28) * 64 + (t + 1)) * 28 + (tid % 28)];

        // barrier B: lgkm-only (red2 visible).
        asm volatile("s_waitcnt lgkmcnt(0)\n\ts_barrier" ::: "memory");

        float mu_r[4], rs_r[4];
#pragma unroll
        for (int r = 0; r < 4; ++r) {
            float s = 0.f, s2 = 0.f;
#pragma unroll
            for (int w2 = 0; w2 < NWAVE; ++w2) {
                float2 e = red2[w2][quad * 4 + r];
                s += e.x; s2 += e.y;
            }
            float mu  = s * (1.f / NET);
            float var = s2 * (1.f / NET) - mu * mu;
            mu_r[r] = mu;
            rs_r[r] = rsqrtf(var + 1e-5f);
        }

        // ---- LN apply + PulseTGAU neuron, write split spikes ----
#pragma unroll
        for (int i = 0; i < NTILE; ++i) {
            int n_i  = (w * NTILE + i) * 16 + l15;
            int base = ((n_i >> 3) * RPB) * 8 + (n_i & 7);
#pragma unroll
            for (int r = 0; r < 4; ++r) {
                int m = quad * 4 + r;
                float cur = (acc[i][r] - mu_r[r]) * rs_r[r] * gam[i] + bet[i];
                float p   = pot[i][r] * 0.95f + cur + intv[i];
                float gp  = p - thrv[i];
                float sg  = sigm(gp * asp[i]);
                float sp  = sigm(gp);
                float gs  = gp * sg;
                float o   = gs * sp;
                pot[i][r] = p - rscv[i] * gs;
                _Float16 h = (_Float16)o;
                Ah[base + m * 8] = h;
                Al[base + m * 8] = (_Float16)(o - (float)h);
            }
        }

        if (do_x) {
            int m = tid / 28, f = tid % 28;
            _Float16 h = (_Float16)xv;
            int ix = ((f >> 3) * RPB + m) * 8 + (f & 7);
            xh[ix] = h; xl[ix] = (_Float16)(xv - (float)h);
        }
    }

    __syncthreads();   // full drain (phantom last-step refills land harmlessly in SB)
    // ---- Classifier epilogue ----
    if (tid < RPB * 10) {
        int r = tid / 10, c = tid - r * 10;
        const float* wc = W_cls + c * NET;
        float s = b_cls[c];
        for (int k = 0; k < NET; ++k) {
            int ix = ((k >> 3) * RPB + r) * 8 + (k & 7);
            float sv = (float)Ah[ix] + (float)Al[ix];
            s = fmaf(sv, wc[k], s);
        }
        out[(size_t)(row0 + r) * 10 + c] = s;
    }
}

extern "C" void kernel_launch(void* const* d_in, const int* in_sizes, int n_in,
                              void* d_out, int out_size, void* d_ws, size_t ws_size,
                              hipStream_t stream)
{
    const float* x      = (const float*)d_in[0];
    const int*   rsteps = (const int*)  d_in[1];
    const float* W_in   = (const float*)d_in[2];
    const float* b_in   = (const float*)d_in[3];
    const float* W_gate = (const float*)d_in[4];
    const float* b_gate = (const float*)d_in[5];
    const float* W_rec  = (const float*)d_in[6];
    const float* ln_g   = (const float*)d_in[7];
    const float* ln_b   = (const float*)d_in[8];
    const float* thr    = (const float*)d_in[9];
    const float* intr   = (const float*)d_in[10];
    const float* steep  = (const float*)d_in[11];
    const float* rsc    = (const float*)d_in[12];
    const float* W_cls  = (const float*)d_in[13];
    const float* b_cls  = (const float*)d_in[14];
    float*       out    = (float*)d_out;

    _Float16* BW  = (_Float16*)d_ws;
    _Float16* Wio = BW + BW_E;

    const int total = BW_E + 4 * WIN_E;
    prep_kernel<<<dim3((total + 255) / 256), dim3(256), 0, stream>>>(
        W_rec, W_in, W_gate, BW, Wio);
    resonator_kernel<<<dim3(NBLK), dim3(NTHR), 0, stream>>>(
        x, rsteps, b_in, b_gate, ln_g, ln_b, thr, intr, steep, rsc,
        W_cls, b_cls, BW, Wio, out);
}